// Round 5
// baseline (437.182 us; speedup 1.0000x reference)
//
#include <hip/hip_runtime.h>
#include <hip/hip_bf16.h>
#include <type_traits>

#define FEAT 128

typedef unsigned int uint32;
typedef unsigned short ushort16;
typedef __attribute__((ext_vector_type(8))) short short8;
typedef __attribute__((ext_vector_type(4))) float v4f;
typedef __attribute__((ext_vector_type(2))) float f32x2;

// ---- bf16 helpers (RNE round; bf16->f32 is exact shift) ---------------------
__device__ __forceinline__ ushort16 f2bf(float f) {
    uint32 u = __float_as_uint(f);
    u += 0x7fffu + ((u >> 16) & 1u);
    return (ushort16)(u >> 16);
}
__device__ __forceinline__ float bflo(uint32 u) { return __uint_as_float(u << 16); }
__device__ __forceinline__ float bfhi(uint32 u) { return __uint_as_float(u & 0xffff0000u); }
__device__ __forceinline__ f32x2 up2(uint32 u) { return (f32x2){bflo(u), bfhi(u)}; }

// ---------------- histogram of col (in-degree, without self-loop) ------------
__global__ void hist_kernel(const int* __restrict__ col, int* __restrict__ counts, int E) {
    int e = blockIdx.x * 256 + threadIdx.x;
    if (e < E) atomicAdd(&counts[col[e]], 1);
}

// ---------------- scan step 1: per-1024-chunk sums ---------------------------
__global__ __launch_bounds__(256) void scan_part(const int* __restrict__ counts,
                                                 int* __restrict__ bsum, int n) {
    __shared__ int s[256];
    int base = blockIdx.x * 1024;
    int t = threadIdx.x;
    int v = 0;
#pragma unroll
    for (int i = 0; i < 4; i++) {
        int idx = base + t * 4 + i;
        if (idx < n) v += counts[idx];
    }
    s[t] = v;
    __syncthreads();
    for (int o = 128; o > 0; o >>= 1) {
        if (t < o) s[t] += s[t + o];
        __syncthreads();
    }
    if (t == 0) bsum[blockIdx.x] = s[0];
}

// ---------------- scan step 2: exclusive scan of block sums (nb <= 128) ------
__global__ void scan_bsum(int* __restrict__ bsum, int nb) {
    __shared__ int s[128];
    int t = threadIdx.x;
    int v0 = (t < nb) ? bsum[t] : 0;
    s[t] = v0;
    __syncthreads();
    for (int o = 1; o < 128; o <<= 1) {
        int v = (t >= o) ? s[t - o] : 0;
        __syncthreads();
        s[t] += v;
        __syncthreads();
    }
    if (t < nb) bsum[t] = s[t] - v0;  // exclusive
}

// ---------------- scan step 3: final offsets + next[] + dinv -----------------
__global__ __launch_bounds__(256) void scan_final(const int* __restrict__ counts,
                                                  const int* __restrict__ bsum,
                                                  int* __restrict__ off, int* __restrict__ nxt,
                                                  float* __restrict__ dinv, int n) {
    __shared__ int s[256];
    int base = blockIdx.x * 1024;
    int t = threadIdx.x;
    int c[4];
    int sum = 0;
#pragma unroll
    for (int i = 0; i < 4; i++) {
        int idx = base + t * 4 + i;
        c[i] = (idx < n) ? counts[idx] : 0;
        sum += c[i];
    }
    int v0 = sum;
    s[t] = sum;
    __syncthreads();
    for (int o = 1; o < 256; o <<= 1) {
        int v = (t >= o) ? s[t - o] : 0;
        __syncthreads();
        s[t] += v;
        __syncthreads();
    }
    int excl = s[t] - v0 + bsum[blockIdx.x];
#pragma unroll
    for (int i = 0; i < 4; i++) {
        int idx = base + t * 4 + i;
        if (idx < n) {
            off[idx] = excl;
            nxt[idx] = excl;
            dinv[idx] = rsqrtf((float)(c[i] + 1));  // +1 = self loop
        }
        excl += c[i];
    }
    if (blockIdx.x == gridDim.x - 1 && t == 255) off[n] = excl;  // == E
}

// ---------------- CSR fill: edge record (src, dinv[src]) packed as uint2 -----
__global__ void fill_kernel(const int* __restrict__ row, const int* __restrict__ col,
                            const float* __restrict__ dinv, int* __restrict__ nxt,
                            uint2* __restrict__ erec, int E) {
    int e = blockIdx.x * 256 + threadIdx.x;
    if (e < E) {
        int c = col[e], r = row[e];
        int p = atomicAdd(&nxt[c], 1);
        erec[p] = make_uint2((uint32)r, __float_as_uint(dinv[r]));
    }
}

// ---------------- convert W0/1/2 (fp32, row-major [k][n]) -> bf16 transposed [n][k]
__global__ __launch_bounds__(256) void cvt_w_kernel(const float* __restrict__ W0,
                                                    const float* __restrict__ W1,
                                                    const float* __restrict__ W2,
                                                    ushort16* __restrict__ Wt) {
    int id = blockIdx.x * 256 + threadIdx.x;
    if (id >= 3 * 16384) return;
    int m = id >> 14;
    int o = id & 16383;
    int ncol = o >> 7;   // output row  (= W column)
    int k = o & 127;     // output col  (= W row)
    const float* W = (m == 0) ? W0 : (m == 1) ? W1 : W2;
    Wt[id] = f2bf(W[(size_t)k * FEAT + ncol]);
}

// ---------------- bf16 MFMA GEMM: Ch = bf16(A @ W), W given transposed -------
// No LDS: the 32 KB Wt matrix is L1-resident, fragments read straight from
// global per use. One 16-row tile per wave; low VGPR (~70) -> high occupancy
// to hide A-load latency (this was the R3/R4 GEMM bottleneck: 1-2 waves/SIMD).
// OPERAND SWAP (verified R4): mfma(Wfrag, Afrag) puts node row in D's n-dim
// (col=lane&15), W cols in m-dim -> direct 8B packed stores.
template <typename T>
__global__ __launch_bounds__(256) void gemm_mfma(const T* __restrict__ A,
                                                 const ushort16* __restrict__ Wt,
                                                 ushort16* __restrict__ Ch, int n) {
    const int t = threadIdx.x;
    const int w = t >> 6;
    const int lane = t & 63;
    const int quad = lane >> 4;
    const int l16 = lane & 15;
    const int tile = blockIdx.x * 4 + w;
    if (tile * 16 >= n) return;  // wave-uniform; no barriers in this kernel
    const int row = tile * 16 + l16;

    // A fragments (MFMA B-operand): lane holds A[row][k=quad*8+ks*32+j]
    short8 a[4];
    if (row < n) {
        if constexpr (std::is_same<T, float>::value) {
#pragma unroll
            for (int ks = 0; ks < 4; ks++) {
                const float* ap = A + (size_t)row * FEAT + quad * 8 + ks * 32;
                float4 f0 = *(const float4*)ap;
                float4 f1 = *(const float4*)(ap + 4);
                short8 v;
                v[0] = f2bf(f0.x); v[1] = f2bf(f0.y); v[2] = f2bf(f0.z); v[3] = f2bf(f0.w);
                v[4] = f2bf(f1.x); v[5] = f2bf(f1.y); v[6] = f2bf(f1.z); v[7] = f2bf(f1.w);
                a[ks] = v;
            }
        } else {
            const ushort16* ap = A + (size_t)row * FEAT + quad * 8;
#pragma unroll
            for (int ks = 0; ks < 4; ks++) a[ks] = *(const short8*)(ap + ks * 32);
        }
    } else {
#pragma unroll
        for (int ks = 0; ks < 4; ks++) a[ks] = (short8)0;
    }

    v4f acc[8];
#pragma unroll
    for (int ct = 0; ct < 8; ct++) acc[ct] = (v4f)0.f;

#pragma unroll
    for (int ct = 0; ct < 8; ct++) {
        const ushort16* wp = Wt + (size_t)(ct * 16 + l16) * FEAT + quad * 8;
#pragma unroll
        for (int ks = 0; ks < 4; ks++) {
            short8 wf = *(const short8*)(wp + ks * 32);  // L1-resident
            acc[ct] = __builtin_amdgcn_mfma_f32_16x16x32_bf16(wf, a[ks], acc[ct], 0, 0, 0);
        }
    }

    if (row < n) {
#pragma unroll
        for (int ct = 0; ct < 8; ct++) {
            uint2 o;
            o.x = (uint32)f2bf(acc[ct][0]) | ((uint32)f2bf(acc[ct][1]) << 16);
            o.y = (uint32)f2bf(acc[ct][2]) | ((uint32)f2bf(acc[ct][3]) << 16);
            *(uint2*)(Ch + (size_t)row * FEAT + ct * 16 + quad * 4) = o;
        }
    }
}

// ---------------- gather-propagate over bf16 table ---------------------------
// H[c] = dinv[c]^2*XW[c] + sum_e dinv[c]*dinv[src_e]*XW[src_e]
// 4 edge-groups x 16 lanes x 16B. Unroll-2: two table rows in flight per group
// (8/wave) to push memory-level parallelism; f32x2 accum -> v_pk_fma_f32.
// mode 0: write bf16; mode 1: leaky_relu(0.01) then bf16; mode 2: write fp32
__global__ __launch_bounds__(256) void gather_kernel(const int* __restrict__ off,
                                                     const uint2* __restrict__ erec,
                                                     const float* __restrict__ dinv,
                                                     const ushort16* __restrict__ XWh,
                                                     ushort16* __restrict__ Hh,
                                                     float* __restrict__ Hf,
                                                     int n, int mode) {
    int node = blockIdx.x * 4 + (threadIdx.x >> 6);
    if (node >= n) return;
    int lane = threadIdx.x & 63;
    int grp = lane >> 4;   // edge group 0..3
    int l16 = lane & 15;   // 16B chunk within row
    float dc = dinv[node];
    const uint4* table = (const uint4*)XWh;  // row = 16 x uint4

    f32x2 acc[4];
    if (grp == 0) {  // self-loop term
        uint4 v = table[(size_t)node * 16 + l16];
        f32x2 w0 = (f32x2){dc * dc, dc * dc};
        acc[0] = w0 * up2(v.x);
        acc[1] = w0 * up2(v.y);
        acc[2] = w0 * up2(v.z);
        acc[3] = w0 * up2(v.w);
    } else {
#pragma unroll
        for (int j = 0; j < 4; j++) acc[j] = (f32x2){0.f, 0.f};
    }

    int s = off[node], e = off[node + 1];
    int i = s + grp;
    for (; i + 4 < e; i += 8) {  // two edges per iteration, both loads in flight
        uint2 er0 = erec[i];
        uint2 er1 = erec[i + 4];
        uint4 u0 = table[(size_t)er0.x * 16 + l16];
        uint4 u1 = table[(size_t)er1.x * 16 + l16];
        float f0 = dc * __uint_as_float(er0.y);
        float f1 = dc * __uint_as_float(er1.y);
        f32x2 n0 = (f32x2){f0, f0};
        f32x2 n1 = (f32x2){f1, f1};
        acc[0] += n0 * up2(u0.x);
        acc[1] += n0 * up2(u0.y);
        acc[2] += n0 * up2(u0.z);
        acc[3] += n0 * up2(u0.w);
        acc[0] += n1 * up2(u1.x);
        acc[1] += n1 * up2(u1.y);
        acc[2] += n1 * up2(u1.z);
        acc[3] += n1 * up2(u1.w);
    }
    if (i < e) {
        uint2 er0 = erec[i];
        uint4 u0 = table[(size_t)er0.x * 16 + l16];
        float f0 = dc * __uint_as_float(er0.y);
        f32x2 n0 = (f32x2){f0, f0};
        acc[0] += n0 * up2(u0.x);
        acc[1] += n0 * up2(u0.y);
        acc[2] += n0 * up2(u0.z);
        acc[3] += n0 * up2(u0.w);
    }

    float b[8] = {acc[0].x, acc[0].y, acc[1].x, acc[1].y,
                  acc[2].x, acc[2].y, acc[3].x, acc[3].y};
    // combine the 4 groups (lane bits 4,5)
#pragma unroll
    for (int j = 0; j < 8; j++) {
        b[j] += __shfl_xor(b[j], 16);
        b[j] += __shfl_xor(b[j], 32);
    }

    if (mode == 2) {
        if (grp < 2) {
            float4 o = (grp == 0) ? make_float4(b[0], b[1], b[2], b[3])
                                  : make_float4(b[4], b[5], b[6], b[7]);
            *(float4*)(Hf + (size_t)node * FEAT + l16 * 8 + grp * 4) = o;
        }
    } else {
        if (mode == 1) {
#pragma unroll
            for (int j = 0; j < 8; j++) b[j] = (b[j] >= 0.f) ? b[j] : 0.01f * b[j];
        }
        if (grp == 0) {
            uint4 o;
            o.x = (uint32)f2bf(b[0]) | ((uint32)f2bf(b[1]) << 16);
            o.y = (uint32)f2bf(b[2]) | ((uint32)f2bf(b[3]) << 16);
            o.z = (uint32)f2bf(b[4]) | ((uint32)f2bf(b[5]) << 16);
            o.w = (uint32)f2bf(b[6]) | ((uint32)f2bf(b[7]) << 16);
            *(uint4*)(Hh + (size_t)node * FEAT + l16 * 8) = o;
        }
    }
}

// ---------------- pooling: out[batch[i]] += H[i]; batch sorted ---------------
__global__ __launch_bounds__(128) void pool_kernel(const float* __restrict__ H,
                                                   const int* __restrict__ batch,
                                                   float* __restrict__ out, int n) {
    int t = threadIdx.x;  // feature
    int i0 = blockIdx.x * 64;
    if (i0 >= n) return;
    int i1 = min(i0 + 64, n);
    float acc = 0.f;
    int g = batch[i0];
    for (int i = i0; i < i1; i++) {
        int b = batch[i];
        if (b != g) {
            atomicAdd(&out[(size_t)g * FEAT + t], acc);
            acc = 0.f;
            g = b;
        }
        acc += H[(size_t)i * FEAT + t];
    }
    atomicAdd(&out[(size_t)g * FEAT + t], acc);
}

extern "C" void kernel_launch(void* const* d_in, const int* in_sizes, int n_in,
                              void* d_out, int out_size, void* d_ws, size_t ws_size,
                              hipStream_t stream) {
    const float* x = (const float*)d_in[0];
    const int* ei = (const int*)d_in[1];
    const int* batch = (const int*)d_in[2];
    const float* W0 = (const float*)d_in[3];
    const float* W1 = (const float*)d_in[4];
    const float* W2 = (const float*)d_in[5];
    float* out = (float*)d_out;

    const int N = in_sizes[0] / FEAT;  // 100000
    const int E = in_sizes[1] / 2;     // 640000

    const int* rowI = ei;
    const int* colI = ei + E;

    char* ws = (char*)d_ws;
    auto take = [&](size_t bytes) {
        char* p = ws;
        ws += (bytes + 15) & ~(size_t)15;
        return p;
    };
    int* counts   = (int*)take((size_t)N * 4);
    int* off      = (int*)take((size_t)(N + 1) * 4);
    int* nxt      = (int*)take((size_t)N * 4);
    float* dinv   = (float*)take((size_t)N * 4);
    int* bsum     = (int*)take(128 * 4);
    uint2* erec   = (uint2*)take((size_t)E * 8);
    ushort16* Wt  = (ushort16*)take((size_t)3 * 16384 * 2);
    ushort16* Hh  = (ushort16*)take((size_t)N * FEAT * 2);
    ushort16* XWh = (ushort16*)take((size_t)N * FEAT * 2);
    float* Hf     = (float*)take((size_t)N * FEAT * 4);

    const int nb = (N + 1023) / 1024;
    const int eb = (E + 255) / 256;

    // ---- weights -> bf16 transposed ----
    cvt_w_kernel<<<(3 * 16384 + 255) / 256, 256, 0, stream>>>(W0, W1, W2, Wt);

    // ---- degree + CSR build ----
    hipMemsetAsync(counts, 0, (size_t)N * 4, stream);
    hist_kernel<<<eb, 256, 0, stream>>>(colI, counts, E);
    scan_part<<<nb, 256, 0, stream>>>(counts, bsum, N);
    scan_bsum<<<1, 128, 0, stream>>>(bsum, nb);
    scan_final<<<nb, 256, 0, stream>>>(counts, bsum, off, nxt, dinv, N);
    fill_kernel<<<eb, 256, 0, stream>>>(rowI, colI, dinv, nxt, erec, E);

    const int nTiles = (N + 15) / 16;
    const int gemmBlocks = (nTiles + 3) / 4;  // one 16-row tile per wave
    const int gatBlocks = (N + 3) / 4;

    // ---- layer 0 (x fp32 -> bf16 fused in GEMM) ----
    gemm_mfma<float><<<gemmBlocks, 256, 0, stream>>>(x, Wt, XWh, N);
    gather_kernel<<<gatBlocks, 256, 0, stream>>>(off, erec, dinv, XWh, Hh, nullptr, N, 0);
    // ---- layer 1 (+leaky on output) ----
    gemm_mfma<ushort16><<<gemmBlocks, 256, 0, stream>>>(Hh, Wt + 16384, XWh, N);
    gather_kernel<<<gatBlocks, 256, 0, stream>>>(off, erec, dinv, XWh, Hh, nullptr, N, 1);
    // ---- layer 2 (fp32 output for pooling precision) ----
    gemm_mfma<ushort16><<<gemmBlocks, 256, 0, stream>>>(Hh, Wt + 2 * 16384, XWh, N);
    gather_kernel<<<gatBlocks, 256, 0, stream>>>(off, erec, dinv, XWh, nullptr, Hf, N, 2);

    // ---- global_add_pool ----
    hipMemsetAsync(out, 0, (size_t)out_size * 4, stream);
    pool_kernel<<<(N + 63) / 64, 128, 0, stream>>>(Hf, batch, out, N);
}

// Round 6
// 396.915 us; speedup vs baseline: 1.1014x; 1.1014x over previous
//
#include <hip/hip_runtime.h>
#include <hip/hip_bf16.h>
#include <type_traits>

#define FEAT 128

typedef unsigned int uint32;
typedef unsigned short ushort16;
typedef __attribute__((ext_vector_type(8))) short short8;
typedef __attribute__((ext_vector_type(4))) float v4f;
typedef __attribute__((ext_vector_type(2))) float f32x2;

// ---- bf16 helpers (RNE round; bf16->f32 is exact shift) ---------------------
__device__ __forceinline__ ushort16 f2bf(float f) {
    uint32 u = __float_as_uint(f);
    u += 0x7fffu + ((u >> 16) & 1u);
    return (ushort16)(u >> 16);
}
__device__ __forceinline__ float bflo(uint32 u) { return __uint_as_float(u << 16); }
__device__ __forceinline__ float bfhi(uint32 u) { return __uint_as_float(u & 0xffff0000u); }
__device__ __forceinline__ f32x2 up2(uint32 u) { return (f32x2){bflo(u), bfhi(u)}; }

// ---------------- histogram of col (in-degree, without self-loop) ------------
__global__ void hist_kernel(const int* __restrict__ col, int* __restrict__ counts, int E) {
    int e = blockIdx.x * 256 + threadIdx.x;
    if (e < E) atomicAdd(&counts[col[e]], 1);
}

// ---------------- scan step 1: per-1024-chunk sums ---------------------------
__global__ __launch_bounds__(256) void scan_part(const int* __restrict__ counts,
                                                 int* __restrict__ bsum, int n) {
    __shared__ int s[256];
    int base = blockIdx.x * 1024;
    int t = threadIdx.x;
    int v = 0;
#pragma unroll
    for (int i = 0; i < 4; i++) {
        int idx = base + t * 4 + i;
        if (idx < n) v += counts[idx];
    }
    s[t] = v;
    __syncthreads();
    for (int o = 128; o > 0; o >>= 1) {
        if (t < o) s[t] += s[t + o];
        __syncthreads();
    }
    if (t == 0) bsum[blockIdx.x] = s[0];
}

// ---------------- scan step 2: exclusive scan of block sums (nb <= 128) ------
__global__ void scan_bsum(int* __restrict__ bsum, int nb) {
    __shared__ int s[128];
    int t = threadIdx.x;
    int v0 = (t < nb) ? bsum[t] : 0;
    s[t] = v0;
    __syncthreads();
    for (int o = 1; o < 128; o <<= 1) {
        int v = (t >= o) ? s[t - o] : 0;
        __syncthreads();
        s[t] += v;
        __syncthreads();
    }
    if (t < nb) bsum[t] = s[t] - v0;  // exclusive
}

// ---------------- scan step 3: final offsets + next[] + dinv -----------------
__global__ __launch_bounds__(256) void scan_final(const int* __restrict__ counts,
                                                  const int* __restrict__ bsum,
                                                  int* __restrict__ off, int* __restrict__ nxt,
                                                  float* __restrict__ dinv, int n) {
    __shared__ int s[256];
    int base = blockIdx.x * 1024;
    int t = threadIdx.x;
    int c[4];
    int sum = 0;
#pragma unroll
    for (int i = 0; i < 4; i++) {
        int idx = base + t * 4 + i;
        c[i] = (idx < n) ? counts[idx] : 0;
        sum += c[i];
    }
    int v0 = sum;
    s[t] = sum;
    __syncthreads();
    for (int o = 1; o < 256; o <<= 1) {
        int v = (t >= o) ? s[t - o] : 0;
        __syncthreads();
        s[t] += v;
        __syncthreads();
    }
    int excl = s[t] - v0 + bsum[blockIdx.x];
#pragma unroll
    for (int i = 0; i < 4; i++) {
        int idx = base + t * 4 + i;
        if (idx < n) {
            off[idx] = excl;
            nxt[idx] = excl;
            dinv[idx] = rsqrtf((float)(c[i] + 1));  // +1 = self loop
        }
        excl += c[i];
    }
    if (blockIdx.x == gridDim.x - 1 && t == 255) off[n] = excl;  // == E
}

// ---------------- CSR fill: edge record (src, dinv[src]) packed as uint2 -----
__global__ void fill_kernel(const int* __restrict__ row, const int* __restrict__ col,
                            const float* __restrict__ dinv, int* __restrict__ nxt,
                            uint2* __restrict__ erec, int E) {
    int e = blockIdx.x * 256 + threadIdx.x;
    if (e < E) {
        int c = col[e], r = row[e];
        int p = atomicAdd(&nxt[c], 1);
        erec[p] = make_uint2((uint32)r, __float_as_uint(dinv[r]));
    }
}

// ---------------- convert W0/1/2 (fp32, row-major [k][n]) -> bf16 transposed [n][k]
__global__ __launch_bounds__(256) void cvt_w_kernel(const float* __restrict__ W0,
                                                    const float* __restrict__ W1,
                                                    const float* __restrict__ W2,
                                                    ushort16* __restrict__ Wt) {
    int id = blockIdx.x * 256 + threadIdx.x;
    if (id >= 3 * 16384) return;
    int m = id >> 14;
    int o = id & 16383;
    int ncol = o >> 7;   // output row  (= W column)
    int k = o & 127;     // output col  (= W row)
    const float* W = (m == 0) ? W0 : (m == 1) ? W1 : W2;
    Wt[id] = f2bf(W[(size_t)k * FEAT + ncol]);
}

// ---------------- bf16 MFMA GEMM: Ch = bf16(A @ W), W given transposed -------
// Each wave owns a 64-column HALF of W in registers (16 short8 frags = 64
// VGPR, loaded once from global -> L2 broadcast; no LDS, no barriers).
// Wave pairs cover a 16-row tile; A software-prefetched across the tile loop.
// Total ~130 VGPR -> 3-4 waves/SIMD (R3=1 blk/CU LDS-bound, R4=2 w/SIMD
// 200-VGPR, R5=rolled vmcnt(0) chain -- all ~45-75us; this decouples).
// OPERAND SWAP (verified R4): mfma(Wfrag, Afrag) -> lane holds 4 consecutive
// W-cols (quad*4+reg) of node row l16 -> direct 8B packed stores.
template <typename T>
__global__ __launch_bounds__(256) void gemm_mfma(const T* __restrict__ A,
                                                 const ushort16* __restrict__ Wt,
                                                 ushort16* __restrict__ Ch, int n) {
    const int t = threadIdx.x;
    const int w = t >> 6;
    const int lane = t & 63;
    const int quad = lane >> 4;
    const int l16 = lane & 15;
    const int colBase = (w & 1) * 64;  // which 64-col half of W this wave owns

    // W fragments (MFMA A-operand): m = W col = colBase+ct*16+l16, k = quad*8+ks*32+j
    short8 wf[4][4];
#pragma unroll
    for (int ct = 0; ct < 4; ct++) {
        const ushort16* wp = Wt + (size_t)(colBase + ct * 16 + l16) * FEAT + quad * 8;
#pragma unroll
        for (int ks = 0; ks < 4; ks++) wf[ct][ks] = *(const short8*)(wp + ks * 32);
    }

    const int nTiles = (n + 15) >> 4;
    const int tStride = gridDim.x * 2;
    int tile = blockIdx.x * 2 + (w >> 1);
    if (tile >= nTiles) return;

    // A-fragment loader (MFMA B-operand): lane holds A[row=tile*16+l16][k=quad*8+ks*32+j]
    auto loadA = [&](int tl, short8 (&a)[4]) {
        const int row = tl * 16 + l16;
        if (row < n) {
            if constexpr (std::is_same<T, float>::value) {
#pragma unroll
                for (int ks = 0; ks < 4; ks++) {
                    const float* ap = A + (size_t)row * FEAT + quad * 8 + ks * 32;
                    float4 f0 = *(const float4*)ap;
                    float4 f1 = *(const float4*)(ap + 4);
                    short8 v;
                    v[0] = f2bf(f0.x); v[1] = f2bf(f0.y); v[2] = f2bf(f0.z); v[3] = f2bf(f0.w);
                    v[4] = f2bf(f1.x); v[5] = f2bf(f1.y); v[6] = f2bf(f1.z); v[7] = f2bf(f1.w);
                    a[ks] = v;
                }
            } else {
                const ushort16* ap = A + (size_t)row * FEAT + quad * 8;
#pragma unroll
                for (int ks = 0; ks < 4; ks++) a[ks] = *(const short8*)(ap + ks * 32);
            }
        } else {
#pragma unroll
            for (int ks = 0; ks < 4; ks++) a[ks] = (short8)0;
        }
    };

    short8 aCur[4];
    loadA(tile, aCur);

    while (tile < nTiles) {
        const int nextTile = tile + tStride;
        short8 aNxt[4];
        if (nextTile < nTiles) loadA(nextTile, aNxt);  // in flight during MFMA below

        v4f acc[4];
#pragma unroll
        for (int ct = 0; ct < 4; ct++) acc[ct] = (v4f)0.f;
#pragma unroll
        for (int ct = 0; ct < 4; ct++)
#pragma unroll
            for (int ks = 0; ks < 4; ks++)
                acc[ct] = __builtin_amdgcn_mfma_f32_16x16x32_bf16(wf[ct][ks], aCur[ks], acc[ct], 0, 0, 0);

        const int row = tile * 16 + l16;
        if (row < n) {
#pragma unroll
            for (int ct = 0; ct < 4; ct++) {
                uint2 o;
                o.x = (uint32)f2bf(acc[ct][0]) | ((uint32)f2bf(acc[ct][1]) << 16);
                o.y = (uint32)f2bf(acc[ct][2]) | ((uint32)f2bf(acc[ct][3]) << 16);
                *(uint2*)(Ch + (size_t)row * FEAT + colBase + ct * 16 + quad * 4) = o;
            }
        }

        tile = nextTile;
#pragma unroll
        for (int ks = 0; ks < 4; ks++) aCur[ks] = aNxt[ks];
    }
}

// ---------------- gather-propagate over bf16 table ---------------------------
// H[c] = dinv[c]^2*XW[c] + sum_e dinv[c]*dinv[src_e]*XW[src_e]
// 4 edge-groups x 16 lanes x 16B, unroll-2. Pinned at ~48us by L2-miss traffic
// (123MB/dispatch served by L3 at ~2.5TB/s) -- R3/R4/R5 MLP variants all equal.
// mode 0: write bf16; mode 1: leaky_relu(0.01) then bf16; mode 2: write fp32
__global__ __launch_bounds__(256) void gather_kernel(const int* __restrict__ off,
                                                     const uint2* __restrict__ erec,
                                                     const float* __restrict__ dinv,
                                                     const ushort16* __restrict__ XWh,
                                                     ushort16* __restrict__ Hh,
                                                     float* __restrict__ Hf,
                                                     int n, int mode) {
    int node = blockIdx.x * 4 + (threadIdx.x >> 6);
    if (node >= n) return;
    int lane = threadIdx.x & 63;
    int grp = lane >> 4;   // edge group 0..3
    int l16 = lane & 15;   // 16B chunk within row
    float dc = dinv[node];
    const uint4* table = (const uint4*)XWh;  // row = 16 x uint4

    f32x2 acc[4];
    if (grp == 0) {  // self-loop term
        uint4 v = table[(size_t)node * 16 + l16];
        f32x2 w0 = (f32x2){dc * dc, dc * dc};
        acc[0] = w0 * up2(v.x);
        acc[1] = w0 * up2(v.y);
        acc[2] = w0 * up2(v.z);
        acc[3] = w0 * up2(v.w);
    } else {
#pragma unroll
        for (int j = 0; j < 4; j++) acc[j] = (f32x2){0.f, 0.f};
    }

    int s = off[node], e = off[node + 1];
    int i = s + grp;
    for (; i + 4 < e; i += 8) {  // two edges per iteration, both loads in flight
        uint2 er0 = erec[i];
        uint2 er1 = erec[i + 4];
        uint4 u0 = table[(size_t)er0.x * 16 + l16];
        uint4 u1 = table[(size_t)er1.x * 16 + l16];
        float f0 = dc * __uint_as_float(er0.y);
        float f1 = dc * __uint_as_float(er1.y);
        f32x2 n0 = (f32x2){f0, f0};
        f32x2 n1 = (f32x2){f1, f1};
        acc[0] += n0 * up2(u0.x);
        acc[1] += n0 * up2(u0.y);
        acc[2] += n0 * up2(u0.z);
        acc[3] += n0 * up2(u0.w);
        acc[0] += n1 * up2(u1.x);
        acc[1] += n1 * up2(u1.y);
        acc[2] += n1 * up2(u1.z);
        acc[3] += n1 * up2(u1.w);
    }
    if (i < e) {
        uint2 er0 = erec[i];
        uint4 u0 = table[(size_t)er0.x * 16 + l16];
        float f0 = dc * __uint_as_float(er0.y);
        f32x2 n0 = (f32x2){f0, f0};
        acc[0] += n0 * up2(u0.x);
        acc[1] += n0 * up2(u0.y);
        acc[2] += n0 * up2(u0.z);
        acc[3] += n0 * up2(u0.w);
    }

    float b[8] = {acc[0].x, acc[0].y, acc[1].x, acc[1].y,
                  acc[2].x, acc[2].y, acc[3].x, acc[3].y};
    // combine the 4 groups (lane bits 4,5)
#pragma unroll
    for (int j = 0; j < 8; j++) {
        b[j] += __shfl_xor(b[j], 16);
        b[j] += __shfl_xor(b[j], 32);
    }

    if (mode == 2) {
        if (grp < 2) {
            float4 o = (grp == 0) ? make_float4(b[0], b[1], b[2], b[3])
                                  : make_float4(b[4], b[5], b[6], b[7]);
            *(float4*)(Hf + (size_t)node * FEAT + l16 * 8 + grp * 4) = o;
        }
    } else {
        if (mode == 1) {
#pragma unroll
            for (int j = 0; j < 8; j++) b[j] = (b[j] >= 0.f) ? b[j] : 0.01f * b[j];
        }
        if (grp == 0) {
            uint4 o;
            o.x = (uint32)f2bf(b[0]) | ((uint32)f2bf(b[1]) << 16);
            o.y = (uint32)f2bf(b[2]) | ((uint32)f2bf(b[3]) << 16);
            o.z = (uint32)f2bf(b[4]) | ((uint32)f2bf(b[5]) << 16);
            o.w = (uint32)f2bf(b[6]) | ((uint32)f2bf(b[7]) << 16);
            *(uint4*)(Hh + (size_t)node * FEAT + l16 * 8) = o;
        }
    }
}

// ---------------- pooling: out[batch[i]] += H[i]; batch sorted ---------------
__global__ __launch_bounds__(128) void pool_kernel(const float* __restrict__ H,
                                                   const int* __restrict__ batch,
                                                   float* __restrict__ out, int n) {
    int t = threadIdx.x;  // feature
    int i0 = blockIdx.x * 64;
    if (i0 >= n) return;
    int i1 = min(i0 + 64, n);
    float acc = 0.f;
    int g = batch[i0];
    for (int i = i0; i < i1; i++) {
        int b = batch[i];
        if (b != g) {
            atomicAdd(&out[(size_t)g * FEAT + t], acc);
            acc = 0.f;
            g = b;
        }
        acc += H[(size_t)i * FEAT + t];
    }
    atomicAdd(&out[(size_t)g * FEAT + t], acc);
}

extern "C" void kernel_launch(void* const* d_in, const int* in_sizes, int n_in,
                              void* d_out, int out_size, void* d_ws, size_t ws_size,
                              hipStream_t stream) {
    const float* x = (const float*)d_in[0];
    const int* ei = (const int*)d_in[1];
    const int* batch = (const int*)d_in[2];
    const float* W0 = (const float*)d_in[3];
    const float* W1 = (const float*)d_in[4];
    const float* W2 = (const float*)d_in[5];
    float* out = (float*)d_out;

    const int N = in_sizes[0] / FEAT;  // 100000
    const int E = in_sizes[1] / 2;     // 640000

    const int* rowI = ei;
    const int* colI = ei + E;

    char* ws = (char*)d_ws;
    auto take = [&](size_t bytes) {
        char* p = ws;
        ws += (bytes + 15) & ~(size_t)15;
        return p;
    };
    int* counts   = (int*)take((size_t)N * 4);
    int* off      = (int*)take((size_t)(N + 1) * 4);
    int* nxt      = (int*)take((size_t)N * 4);
    float* dinv   = (float*)take((size_t)N * 4);
    int* bsum     = (int*)take(128 * 4);
    uint2* erec   = (uint2*)take((size_t)E * 8);
    ushort16* Wt  = (ushort16*)take((size_t)3 * 16384 * 2);
    ushort16* Hh  = (ushort16*)take((size_t)N * FEAT * 2);
    ushort16* XWh = (ushort16*)take((size_t)N * FEAT * 2);
    float* Hf     = (float*)take((size_t)N * FEAT * 4);

    const int nb = (N + 1023) / 1024;
    const int eb = (E + 255) / 256;

    // ---- weights -> bf16 transposed ----
    cvt_w_kernel<<<(3 * 16384 + 255) / 256, 256, 0, stream>>>(W0, W1, W2, Wt);

    // ---- degree + CSR build ----
    hipMemsetAsync(counts, 0, (size_t)N * 4, stream);
    hist_kernel<<<eb, 256, 0, stream>>>(colI, counts, E);
    scan_part<<<nb, 256, 0, stream>>>(counts, bsum, N);
    scan_bsum<<<1, 128, 0, stream>>>(bsum, nb);
    scan_final<<<nb, 256, 0, stream>>>(counts, bsum, off, nxt, dinv, N);
    fill_kernel<<<eb, 256, 0, stream>>>(rowI, colI, dinv, nxt, erec, E);

    const int gemmBlocks = 1024;  // 4096 waves; ~3 (tile,half) items each
    const int gatBlocks = (N + 3) / 4;

    // ---- layer 0 (x fp32 -> bf16 fused in GEMM) ----
    gemm_mfma<float><<<gemmBlocks, 256, 0, stream>>>(x, Wt, XWh, N);
    gather_kernel<<<gatBlocks, 256, 0, stream>>>(off, erec, dinv, XWh, Hh, nullptr, N, 0);
    // ---- layer 1 (+leaky on output) ----
    gemm_mfma<ushort16><<<gemmBlocks, 256, 0, stream>>>(Hh, Wt + 16384, XWh, N);
    gather_kernel<<<gatBlocks, 256, 0, stream>>>(off, erec, dinv, XWh, Hh, nullptr, N, 1);
    // ---- layer 2 (fp32 output for pooling precision) ----
    gemm_mfma<ushort16><<<gemmBlocks, 256, 0, stream>>>(Hh, Wt + 2 * 16384, XWh, N);
    gather_kernel<<<gatBlocks, 256, 0, stream>>>(off, erec, dinv, XWh, nullptr, Hf, N, 2);

    // ---- global_add_pool ----
    hipMemsetAsync(out, 0, (size_t)out_size * 4, stream);
    pool_kernel<<<(N + 63) / 64, 128, 0, stream>>>(Hf, batch, out, N);
}